// Round 1
// 407.765 us; speedup vs baseline: 1.0498x; 1.0498x over previous
//
#include <hip/hip_runtime.h>
#include <stdint.h>

#define TT 300
#define DD 40
#define SB 8
#define AROW 200           // halfwords per A row (192 data + pad); word stride 100 -> bank stride 4 -> 2-way = free
#define ABUF (16 * AROW)   // 3200 halfwords per A buffer

typedef __attribute__((ext_vector_type(8))) short short8;
typedef __attribute__((ext_vector_type(4))) float f32x4;

__device__ __forceinline__ ushort f2bf(float f) {
  uint32_t b = __float_as_uint(f);
  b += 0x7FFFu + ((b >> 16) & 1u);   // RNE
  return (ushort)(b >> 16);
}

// K layout (192 = 6 ktiles of 32):
//   k  0..39  : x_t
//   k 40,41   : 1.0 (bf16) -> bias hi/lo folded into the matmul
//   k 42..63  : zero
//   k 64..191 : h interleaved: 64+2u = h_hi(u), 65+2u = h_lo(u); both use W row 40+u
// Column permutation (within wave w's 64 cols): cc = g*16 + u_local  -> ntile g holds gate g
//   => after MFMA, lane (n = lane&15) holds the full (i,j,f,o) quad of unit
//      u = w*16 + (lane&15) in acc0..acc3, at rows (lane>>4)*4 + r.
// Sample row remap: sample s lives in A row 4*(s>>1) + (s&1)  (rows {0,1,4,5,8,9,12,13})
//   => every lane group q = lane>>4 sees its 2 samples (2q, 2q+1) at regs r=0,1.
__global__ __launch_bounds__(256, 1) void lstm_mfma_kernel(
    const float* __restrict__ X, const int* __restrict__ seqlen,
    const float* __restrict__ Wk, const float* __restrict__ bias,
    float* __restrict__ hfin)
{
  __shared__ ushort wstage[64 * 192];   // 24 KB, init-only staging (one wave's 64 cols)
  __shared__ ushort Ash[2 * ABUF];      // 12.8 KB, double-buffered A (bf16)

  const int tid = threadIdx.x;
  const int wv = tid >> 6, lane = tid & 63;
  const int s0 = blockIdx.x * SB;

  for (int i = tid; i < 2 * ABUF; i += 256) Ash[i] = 0;

  // ---- stage B fragments into registers (24 frags = 96 VGPRs/wave) ----
  // B[k][n] fragment layout: n = lane&15, k = ktile*32 + (lane>>4)*8 + j
  short8 Bf[6][4];
  for (int c = 0; c < 4; ++c) {
    __syncthreads();   // zero-loop done (c=0); wave c-1's frag reads drained (lgkmcnt(0) before s_barrier)
    for (int i = tid; i < 64 * 192; i += 256) {
      int cc = i & 63, kp = i >> 6;
      int g = cc >> 4, u = c * 16 + (cc & 15);
      int col = g * 64 + u;
      ushort v = 0;
      if (kp < 40) {
        v = f2bf(Wk[kp * 256 + col]);
      } else if (kp < 42) {               // bias as ones-row weights, hi + lo residual
        float bv = bias[col] + ((g == 2) ? 1.0f : 0.0f);   // forget-gate +1
        ushort hi = f2bf(bv);
        v = (kp == 40) ? hi : f2bf(bv - __uint_as_float((uint32_t)hi << 16));
      } else if (kp >= 64) {
        v = f2bf(Wk[(40 + ((kp - 64) >> 1)) * 256 + col]); // hi and lo share the weight row
      }
      wstage[cc * 192 + kp] = v;
    }
    __syncthreads();
    if (wv == c) {
      #pragma unroll
      for (int kt = 0; kt < 6; ++kt) {
        int kk = kt * 32 + (lane >> 4) * 8;
        #pragma unroll
        for (int g = 0; g < 4; ++g)
          Bf[kt][g] = *reinterpret_cast<const short8*>(
              &wstage[(g * 16 + (lane & 15)) * 192 + kk]);
      }
    }
  }

  // ---- per-lane ownership ----
  const int u = wv * 16 + (lane & 15);
  const int q = lane >> 4;
  const int sl0 = 2 * q, sl1 = sl0 + 1;
  const int len0 = seqlen[s0 + sl0], len1 = seqlen[s0 + sl1];

  int ml = seqlen[s0 + (lane & 7)];            // block-max seqlen (values repeat every 8 lanes)
  #pragma unroll
  for (int off = 1; off < 8; off <<= 1) ml = max(ml, __shfl_xor(ml, off));

  // x prefetch: 320 values/step; thread covers i=tid and (tid<64) i=tid+256
  const int iA = tid, iB = 256 + tid;
  const int sA = (iA * 205) >> 13, dA = iA - sA * 40;
  int sB = (iB * 205) >> 13; if (sB > 7) sB = 7;
  const int dB = iB - sB * 40;
  const int rA = 4 * (sA >> 1) + (sA & 1), rB = 4 * (sB >> 1) + (sB & 1);
  const float* pA = X + (size_t)(s0 + sA) * (TT * DD) + dA;
  const float* pB = X + (size_t)(s0 + sB) * (TT * DD) + dB;
  const bool hasB = (iB < SB * DD);
  const int xiA = rA * AROW + dA, xiB = rB * AROW + dB;

  // ones at k=40,41 for the 8 real rows, BOTH buffers (never overwritten afterwards)
  if (tid < 16) {
    int s = tid & 7, b = tid >> 3;
    int row = 4 * (s >> 1) + (s & 1);
    Ash[b * ABUF + row * AROW + 40] = 0x3F80;
    Ash[b * ABUF + row * AROW + 41] = 0x3F80;
  }
  Ash[xiA] = f2bf(pA[0]);                      // x_0 into buffer 0
  if (hasB) Ash[xiB] = f2bf(pB[0]);
  __syncthreads();
  pA += DD; pB += DD;

  float c0 = 0.f, c1 = 0.f, hf0 = 0.f, hf1 = 0.f;
  int rb = 0, wb = ABUF;
  const int afb = (lane & 15) * AROW + q * 8;
  const int hw0 = (q * 4) * AROW + 64 + 2 * u;       // row 4q   (sample sl0)
  const int hw1 = (q * 4 + 1) * AROW + 64 + 2 * u;   // row 4q+1 (sample sl1)

  for (int t = 0; t < ml; ++t) {
    // A fragments: A[m=lane&15][k = kt*32 + q*8 + j]   (2-way bank alias only -> free)
    short8 Af[6];
    #pragma unroll
    for (int kt = 0; kt < 6; ++kt)
      Af[kt] = *reinterpret_cast<const short8*>(&Ash[rb + afb + kt * 32]);

    const bool pre = (t + 1 < ml);
    float xnA = 0.f, xnB = 0.f;
    if (pre) {
      xnA = pA[0]; pA += DD;
      if (hasB) { xnB = pB[0]; pB += DD; }
    }

    f32x4 zero4 = {0.f, 0.f, 0.f, 0.f};
    f32x4 acc0 = zero4, acc1 = zero4, acc2 = zero4, acc3 = zero4;
    #pragma unroll
    for (int kt = 0; kt < 6; ++kt) {
      acc0 = __builtin_amdgcn_mfma_f32_16x16x32_bf16(Af[kt], Bf[kt][0], acc0, 0, 0, 0);
      acc1 = __builtin_amdgcn_mfma_f32_16x16x32_bf16(Af[kt], Bf[kt][1], acc1, 0, 0, 0);
      acc2 = __builtin_amdgcn_mfma_f32_16x16x32_bf16(Af[kt], Bf[kt][2], acc2, 0, 0, 0);
      acc3 = __builtin_amdgcn_mfma_f32_16x16x32_bf16(Af[kt], Bf[kt][3], acc3, 0, 0, 0);
    }

    // acc0=i acc1=j acc2=f acc3=o (bias already included); r=0 -> sl0, r=1 -> sl1.
    // sigm(i)*tanh(j) = (Ej-1) * rcp((1+Ei)(1+Ej));  tanh(nc)*sigm(o) likewise.
    float Ef0 = __expf(-acc2[0]), Ei0 = __expf(-acc0[0]), Ej0 = __expf(2.f * acc1[0]);
    float nc0 = fmaf(c0, __builtin_amdgcn_rcpf(1.f + Ef0),
                     (Ej0 - 1.f) * __builtin_amdgcn_rcpf((1.f + Ei0) * (1.f + Ej0)));
    float En0 = __expf(2.f * fminf(nc0, 44.f)), Eo0 = __expf(-acc3[0]);
    float nh0 = (En0 - 1.f) * __builtin_amdgcn_rcpf((1.f + En0) * (1.f + Eo0));

    float Ef1 = __expf(-acc2[1]), Ei1 = __expf(-acc0[1]), Ej1 = __expf(2.f * acc1[1]);
    float nc1 = fmaf(c1, __builtin_amdgcn_rcpf(1.f + Ef1),
                     (Ej1 - 1.f) * __builtin_amdgcn_rcpf((1.f + Ei1) * (1.f + Ej1)));
    float En1 = __expf(2.f * fminf(nc1, 44.f)), Eo1 = __expf(-acc3[1]);
    float nh1 = (En1 - 1.f) * __builtin_amdgcn_rcpf((1.f + En1) * (1.f + Eo1));

    c0 = nc0; c1 = nc1;
    if (t == len0 - 1) hf0 = nh0;
    if (t == len1 - 1) hf1 = nh1;

    // h feedback as bf16 hi+lo, packed into one b32 write per sample, into the NEXT buffer
    ushort hh0 = f2bf(nh0);
    ushort hl0 = f2bf(nh0 - __uint_as_float((uint32_t)hh0 << 16));
    ushort hh1 = f2bf(nh1);
    ushort hl1 = f2bf(nh1 - __uint_as_float((uint32_t)hh1 << 16));
    *reinterpret_cast<uint32_t*>(&Ash[wb + hw0]) = (uint32_t)hh0 | ((uint32_t)hl0 << 16);
    *reinterpret_cast<uint32_t*>(&Ash[wb + hw1]) = (uint32_t)hh1 | ((uint32_t)hl1 << 16);
    if (pre) {
      Ash[wb + xiA] = f2bf(xnA);
      if (hasB) Ash[wb + xiB] = f2bf(xnB);
    }
    __syncthreads();   // single barrier/step: publishes buf[t+1], retires reads of buf[t]
    rb ^= ABUF; wb ^= ABUF;
  }

  hfin[(size_t)(s0 + sl0) * 64 + u] = hf0;
  hfin[(size_t)(s0 + sl1) * 64 + u] = hf1;
}

// head: 16 samples per block (128 blocks) -> W2 read 128x instead of 2048x
__global__ __launch_bounds__(256, 1) void head_kernel(
    const float* __restrict__ hfin,
    const float* __restrict__ W1, const float* __restrict__ b1,
    const float* __restrict__ gamma, const float* __restrict__ beta,
    const float* __restrict__ mmean, const float* __restrict__ mvar,
    const float* __restrict__ W2, const float* __restrict__ b2,
    float* __restrict__ out)
{
  __shared__ float hl[16 * 64];     // 4 KB
  __shared__ float d1t[128 * 20];   // transposed d1 [k][s], stride 20 (16B-aligned)
  __shared__ float lg[16 * 516];    // 33 KB logits
  const int tid = threadIdx.x;
  const int b0 = blockIdx.x * 16;

  for (int i = tid; i < 16 * 64; i += 256) hl[i] = hfin[(size_t)b0 * 64 + i];
  __syncthreads();

  { // dense1 + BN + ReLU: thread = (col j, sample-group sg), 8 samples each
    const int j = tid & 127, sg = tid >> 7;
    float acc[8];
    const float bb = b1[j];
    #pragma unroll
    for (int s = 0; s < 8; ++s) acc[s] = bb;
    for (int k = 0; k < 64; ++k) {
      float w = W1[k * 128 + j];
      #pragma unroll
      for (int s = 0; s < 8; ++s) acc[s] = fmaf(hl[(sg * 8 + s) * 64 + k], w, acc[s]);
    }
    const float ga = gamma[j], be = beta[j], mm = mmean[j];
    const float iv = rsqrtf(mvar[j] + 1e-3f);
    #pragma unroll
    for (int s = 0; s < 8; ++s) {
      float v = fmaxf(acc[s], 0.f);
      d1t[j * 20 + sg * 8 + s] = ga * (v - mm) * iv + be;
    }
  }
  __syncthreads();

  { // logits: thread owns cols 2*tid, 2*tid+1 for all 16 samples
    const int cA = tid * 2;
    float accA[16], accB[16];
    const float bA = b2[cA], bB = b2[cA + 1];
    #pragma unroll
    for (int s = 0; s < 16; ++s) { accA[s] = bA; accB[s] = bB; }
    for (int k = 0; k < 128; ++k) {
      const float2 w = *reinterpret_cast<const float2*>(&W2[k * 512 + cA]);
      const f32x4 dq0 = *reinterpret_cast<const f32x4*>(&d1t[k * 20]);
      const f32x4 dq1 = *reinterpret_cast<const f32x4*>(&d1t[k * 20 + 4]);
      const f32x4 dq2 = *reinterpret_cast<const f32x4*>(&d1t[k * 20 + 8]);
      const f32x4 dq3 = *reinterpret_cast<const f32x4*>(&d1t[k * 20 + 12]);
      #pragma unroll
      for (int s = 0; s < 4; ++s) {
        accA[s]      = fmaf(dq0[s], w.x, accA[s]);      accB[s]      = fmaf(dq0[s], w.y, accB[s]);
        accA[s + 4]  = fmaf(dq1[s], w.x, accA[s + 4]);  accB[s + 4]  = fmaf(dq1[s], w.y, accB[s + 4]);
        accA[s + 8]  = fmaf(dq2[s], w.x, accA[s + 8]);  accB[s + 8]  = fmaf(dq2[s], w.y, accB[s + 8]);
        accA[s + 12] = fmaf(dq3[s], w.x, accA[s + 12]); accB[s + 12] = fmaf(dq3[s], w.y, accB[s + 12]);
      }
    }
    #pragma unroll
    for (int s = 0; s < 16; ++s) {
      lg[s * 516 + cA]     = accA[s];
      lg[s * 516 + cA + 1] = accB[s];
    }
  }
  __syncthreads();

  { // softmax: wave handles 4 samples, 8 cols/lane
    const int w = tid >> 6, lane = tid & 63;
    #pragma unroll
    for (int si = 0; si < 4; ++si) {
      const int s = w * 4 + si;
      float v[8];
      float m = -3.4e38f;
      #pragma unroll
      for (int i = 0; i < 8; ++i) { v[i] = lg[s * 516 + lane + 64 * i]; m = fmaxf(m, v[i]); }
      #pragma unroll
      for (int off = 1; off < 64; off <<= 1) m = fmaxf(m, __shfl_xor(m, off));
      float sum = 0.f;
      #pragma unroll
      for (int i = 0; i < 8; ++i) { v[i] = __expf(v[i] - m); sum += v[i]; }
      #pragma unroll
      for (int off = 1; off < 64; off <<= 1) sum += __shfl_xor(sum, off);
      const float inv = __builtin_amdgcn_rcpf(sum);
      #pragma unroll
      for (int i = 0; i < 8; ++i)
        out[(size_t)(b0 + s) * 512 + lane + 64 * i] = v[i] * inv;
    }
  }
}

extern "C" void kernel_launch(void* const* d_in, const int* in_sizes, int n_in,
                              void* d_out, int out_size, void* d_ws, size_t ws_size,
                              hipStream_t stream) {
  const float* X      = (const float*)d_in[0];
  const int*   seqlen = (const int*)d_in[1];
  const float* Wk     = (const float*)d_in[2];
  const float* bias   = (const float*)d_in[3];
  const float* W1     = (const float*)d_in[4];
  const float* b1     = (const float*)d_in[5];
  const float* gam    = (const float*)d_in[6];
  const float* bet    = (const float*)d_in[7];
  const float* mmean  = (const float*)d_in[8];
  const float* mvar   = (const float*)d_in[9];
  const float* W2     = (const float*)d_in[10];
  const float* b2     = (const float*)d_in[11];
  float* out  = (float*)d_out;
  float* hfin = (float*)d_ws;   // 2048*64 fp32 = 512 KB

  lstm_mfma_kernel<<<dim3(256), dim3(256), 0, stream>>>(X, seqlen, Wk, bias, hfin);
  head_kernel<<<dim3(128), dim3(256), 0, stream>>>(hfin, W1, b1, gam, bet,
                                                   mmean, mvar, W2, b2, out);
}